// Round 10
// baseline (143.763 us; speedup 1.0000x reference)
//
#include <hip/hip_runtime.h>
#include <hip/hip_bf16.h>

typedef __attribute__((ext_vector_type(8))) short short8;
typedef __attribute__((ext_vector_type(4))) float f32x4;

// ---------------- helpers ----------------
__device__ __forceinline__ ushort f2b(float f) {
    __hip_bfloat16 h = __float2bfloat16(f);
    return *reinterpret_cast<ushort*>(&h);
}
__device__ __forceinline__ float b2f(ushort u) {
    return __uint_as_float(((unsigned)u) << 16);
}
__device__ __forceinline__ void gload16(const ushort* g, ushort* l) {
    __builtin_amdgcn_global_load_lds(
        (const __attribute__((address_space(1))) void*)g,
        (__attribute__((address_space(3))) void*)l, 16, 0, 0);
}

// ============================================================================
// QKV: 128x192-tile NT GEMM, BK=32, 3-slot ring (60 KB -> 2 blocks/CU),
// grid 1024 = EXACTLY 2 scheduling rounds at 512 slots (r9's 768/512 = 1.5
// rounds cost 25% makespan in tail idle). Same proven ring ledger / swizzle.
// 512 thr = 8 waves (2M x 4N), 64x48 per wave (acc[4][3]).
// B-tile = 12 KB = 1.5 units: all waves stage unit0, waves 0-3 stage the
// half-unit -> per-wave counted vmcnt (3 for w<4, 2 for w>=4).
// ============================================================================
__global__ __launch_bounds__(512, 4) void qkv_gemm(
    const ushort* __restrict__ xb, const ushort* __restrict__ Wcat,
    const float* __restrict__ bk, const float* __restrict__ bq, const float* __restrict__ bv,
    ushort* __restrict__ Kb, ushort* __restrict__ Qb, ushort* __restrict__ Vt) {
    constexpr int T = 2048, C = 1024, K = 1024, NT = 32;
    __shared__ ushort smem[30720];  // 60 KB = 3 slots x 10240 ush (A 8KB + B 12KB)

    const int tid = threadIdx.x;
    const int l = tid & 63, w = tid >> 6;
    const int wm = (w >> 2) * 64, wn = (w & 3) * 48;   // 2M x 4N, 64x48/wave
    const int lr = l & 15, lk = l >> 4;

    const int b = blockIdx.x;                   // 1024 = 8*128
    const int wg = (b & 7) * 128 + (b >> 3);    // XCD-bijective
    const int m0 = (wg >> 4) * 128, n0 = (wg & 15) * 192;

    // staging coords (pre-swizzled source; linear LDS dest)
    const int srow = w * 16 + (l >> 2);                      // 0..127
    const int scb = ((l & 3) << 4) ^ ((l & 32) ? 32 : 0);    // swizzled byte col
    const ushort* gA  = xb + (size_t)(m0 + srow) * K + (scb >> 1);
    const ushort* gB  = Wcat + (size_t)(n0 + srow) * K + (scb >> 1);        // B rows 0-127
    const ushort* gB2 = Wcat + (size_t)(n0 + 128 + srow) * K + (scb >> 1);  // rows 128-191 (w<4)

    // ds_read per-lane base (ushort units), swizzled
    const int LB = lr * 32 + ((lk << 3) ^ ((lr >= 8) ? 16 : 0));

    f32x4 acc[4][3] = {};

    // slot layout (ushort offsets): A rows0-127 @0..4095; B rows0-127 @4096..8191;
    // B rows128-191 @8192..10239.
#define STAGEQ(tt, sl)                                                    \
    {                                                                     \
        const int _ko = (tt) * 32;                                        \
        ushort* _s = smem + (sl) * 10240;                                 \
        gload16(gA + _ko,  _s + w * 512);                                 \
        gload16(gB + _ko,  _s + 4096 + w * 512);                          \
        if (w < 4) gload16(gB2 + _ko, _s + 8192 + w * 512);               \
    }
#define WAIT_KEEP1                                                        \
    {                                                                     \
        if (w < 4) asm volatile("s_waitcnt vmcnt(3)" ::: "memory");       \
        else       asm volatile("s_waitcnt vmcnt(2)" ::: "memory");       \
    }

    STAGEQ(0, 0);
    STAGEQ(1, 1);
    WAIT_KEEP1;                     // drain STAGE(0), keep STAGE(1)
    __builtin_amdgcn_s_barrier();
    asm volatile("" ::: "memory");

    int sc = 0, ss = 2;
    for (int t = 0; t < NT; ++t) {
        const ushort* slot = smem + sc * 10240;
        const ushort* Ab = slot + (wm >> 4) * 512 + LB;
        const ushort* Bb = slot + 4096 + (wn >> 4) * 512 + LB;
        short8 af[4], bf3[3];
#pragma unroll
        for (int f = 0; f < 4; ++f) af[f] = *reinterpret_cast<const short8*>(Ab + f * 512);
#pragma unroll
        for (int g = 0; g < 3; ++g) bf3[g] = *reinterpret_cast<const short8*>(Bb + g * 512);
        if (t + 2 < NT) STAGEQ(t + 2, ss);
        __builtin_amdgcn_s_setprio(1);
#pragma unroll
        for (int f = 0; f < 4; ++f)
#pragma unroll
            for (int g = 0; g < 3; ++g)
                acc[f][g] = __builtin_amdgcn_mfma_f32_16x16x32_bf16(af[f], bf3[g], acc[f][g], 0, 0, 0);
        __builtin_amdgcn_s_setprio(0);
        if (t + 1 < NT) {
            if (t + 2 < NT) { WAIT_KEEP1; }
            else            asm volatile("s_waitcnt vmcnt(0)" ::: "memory");
            __builtin_amdgcn_s_barrier();
            asm volatile("" ::: "memory");
        }
        sc = (sc == 2) ? 0 : sc + 1;
        ss = (ss == 2) ? 0 : ss + 1;
    }
#undef STAGEQ
#undef WAIT_KEEP1

    // ---- epilogue: per-frag zsel (192-wide tiles straddle the C=1024 splits;
    // frag bases are 16-aligned so each frag lies wholly in one output) ----
    const int zb = (m0 + wm) >> 11;
    const int s0 = (m0 + wm) & 2047;
    ushort* Vz = Vt + (size_t)zb * C * T;
#pragma unroll
    for (int g = 0; g < 3; ++g) {
        const int nbase = n0 + wn + g * 16;
        const int zf = nbase >> 10;
        const int cf = (nbase & 1023) + lr;
        if (zf < 2) {
            ushort* O = (zf == 0) ? Kb : Qb;
            const float badd = ((zf == 0) ? bk : bq)[cf];
#pragma unroll
            for (int f = 0; f < 4; ++f)
#pragma unroll
                for (int rr = 0; rr < 4; ++rr) {
                    const int gr = m0 + wm + f * 16 + lk * 4 + rr;
                    O[(size_t)gr * C + cf] = f2b(acc[f][g][rr] + badd);
                }
        } else {
            const float badd = bv[cf];
#pragma unroll
            for (int f = 0; f < 4; ++f) {
                const int s = s0 + f * 16 + lk * 4;
                ushort tmp[4];
#pragma unroll
                for (int rr = 0; rr < 4; ++rr) tmp[rr] = f2b(acc[f][g][rr] + badd);
                *reinterpret_cast<uint2*>(Vz + (size_t)cf * T + s) =
                    *reinterpret_cast<uint2*>(tmp);
            }
        }
    }
}

// ============================================================================
// 3-slot ring 128x128 NT GEMM for scores / PV.
// MODE 1 = scores: writes p' = exp(s/32) (0 above diag in diag blocks) AND
//          accumulates row-sums of P' into rowsum[] (shfl reduce + atomicAdd).
// MODE 2 = PV: plain GEMM; epilogue y = acc / rowsum[row] (no ones-MFMA).
// ============================================================================
template <int MODE>
__global__ __launch_bounds__(256, 3) void gemm_ring(
    const ushort* __restrict__ Kb, const ushort* __restrict__ Qb,
    const ushort* __restrict__ Vt, ushort* __restrict__ Sb,
    float* __restrict__ rowsum, float* __restrict__ out) {
    constexpr int T = 2048, C = 1024;
    __shared__ ushort smem[24576];  // 48 KB

    const int tid = threadIdx.x;
    const int l = tid & 63, w = tid >> 6;
    const int wm = (w >> 1) * 64, wn = (w & 1) * 64;
    const int lr = l & 15, lk = l >> 4;

    int m0, n0, nt, iblk = 0, jblk = 0, z = 0;
    const ushort *Au, *Bu;
    int ldA, ldB;
    if constexpr (MODE == 1) {
        const int wg0 = blockIdx.x;                  // 544 = 8*68
        const int wg = (wg0 & 7) * 68 + (wg0 >> 3);
        z = wg / 136; const int t136 = wg % 136;
        int i = (int)((sqrtf(8.f * t136 + 1.f) - 1.f) * 0.5f);
        while ((i + 1) * (i + 2) / 2 <= t136) ++i;
        while (i * (i + 1) / 2 > t136) --i;
        const int j = t136 - i * (i + 1) / 2;
        iblk = i; jblk = j;
        m0 = i * 128; n0 = j * 128;
        Au = Qb + (size_t)z * T * C + (size_t)m0 * C; ldA = C;
        Bu = Kb + (size_t)z * T * C + (size_t)n0 * C; ldB = C;
        nt = 32;
    } else {
        const int wg0 = blockIdx.x;                  // 512 = 8*64
        const int wg = (wg0 & 7) * 64 + (wg0 >> 3);
        const int half = wg >> 8, s2 = wg & 255;
        z = s2 >> 6; const int r6 = s2 & 63;
        const int nb = r6 & 7, ii = r6 >> 3;
        const int i = half ? (15 - ii) : ii;
        iblk = i;
        m0 = i * 128; n0 = nb * 128;
        Au = Sb + (size_t)z * T * T + (size_t)m0 * T; ldA = T;
        Bu = Vt + (size_t)z * C * T + (size_t)n0 * T; ldB = T;
        nt = 4 * (i + 1);
    }

    const int srow = w * 16 + (l >> 2);
    const int scb = ((l & 3) << 4) ^ ((l >= 32) ? 32 : 0);
    const ushort* gA = Au + (size_t)srow * ldA + (scb >> 1);
    const ushort* gB = Bu + (size_t)srow * ldB + (scb >> 1);
    const size_t a64 = (size_t)64 * ldA, b64 = (size_t)64 * ldB;
    const int LBu = lr * 32 + ((lk << 3) ^ ((lr >= 8) ? 16 : 0));

    f32x4 acc[4][4] = {};

#define STAGE(tt, sl)                                                    \
    {                                                                    \
        const int _ko = (tt) * 32;                                       \
        ushort* _d = smem + (sl) * 8192 + w * 512;                       \
        gload16(gA + _ko,        _d);                                    \
        gload16(gA + a64 + _ko,  _d + 2048);                             \
        gload16(gB + _ko,        _d + 4096);                             \
        gload16(gB + b64 + _ko,  _d + 6144);                             \
    }

    STAGE(0, 0);
    STAGE(1, 1);
    asm volatile("s_waitcnt vmcnt(4)" ::: "memory");
    __builtin_amdgcn_s_barrier();
    asm volatile("" ::: "memory");

    int sc = 0, ss = 2;
    for (int t = 0; t < nt; ++t) {
        const ushort* As = smem + sc * 8192 + (wm >> 4) * 512 + LBu;
        const ushort* Bs = smem + sc * 8192 + 4096 + (wn >> 4) * 512 + LBu;
        short8 af[4], bf[4];
#pragma unroll
        for (int q = 0; q < 4; ++q) {
            af[q] = *reinterpret_cast<const short8*>(As + q * 512);
            bf[q] = *reinterpret_cast<const short8*>(Bs + q * 512);
        }
        if (t + 2 < nt) STAGE(t + 2, ss);
        __builtin_amdgcn_s_setprio(1);
#pragma unroll
        for (int mf = 0; mf < 4; ++mf)
#pragma unroll
            for (int nf = 0; nf < 4; ++nf)
                acc[mf][nf] = __builtin_amdgcn_mfma_f32_16x16x32_bf16(af[mf], bf[nf], acc[mf][nf], 0, 0, 0);
        __builtin_amdgcn_s_setprio(0);
        if (t + 1 < nt) {
            if (t + 2 < nt) asm volatile("s_waitcnt vmcnt(4)" ::: "memory");
            else            asm volatile("s_waitcnt vmcnt(0)" ::: "memory");
            __builtin_amdgcn_s_barrier();
            asm volatile("" ::: "memory");
        }
        sc = (sc == 2) ? 0 : sc + 1;
        ss = (ss == 2) ? 0 : ss + 1;
    }
#undef STAGE

    if constexpr (MODE == 1) {
        // write p' = exp(s/32) (0 above diag on diag blocks) + row-sum accumulate
        ushort* Sp = Sb + (size_t)z * T * T;
        const bool diag = (iblk == jblk);
        float rp[4][4];  // [mf][rr] partial row sums (this lane's 4 cols)
#pragma unroll
        for (int mf = 0; mf < 4; ++mf)
#pragma unroll
            for (int rr = 0; rr < 4; ++rr) rp[mf][rr] = 0.f;
#pragma unroll
        for (int mf = 0; mf < 4; ++mf)
#pragma unroll
            for (int nf = 0; nf < 4; ++nf) {
                const int gc = n0 + wn + nf * 16 + lr;
#pragma unroll
                for (int rr = 0; rr < 4; ++rr) {
                    const int gr = m0 + wm + mf * 16 + lk * 4 + rr;
                    float p = __expf(acc[mf][nf][rr] * 0.03125f);
                    if (diag && gc > gr) p = 0.f;
                    const ushort us = f2b(p);
                    Sp[(size_t)gr * T + gc] = us;
                    rp[mf][rr] += b2f(us);   // rounded value: matches PV numerator
                }
            }
        // reduce across the 16 lanes (lr) sharing each row, then one atomic/row
#pragma unroll
        for (int mf = 0; mf < 4; ++mf)
#pragma unroll
            for (int rr = 0; rr < 4; ++rr) {
                float v = rp[mf][rr];
                v += __shfl_xor(v, 1);
                v += __shfl_xor(v, 2);
                v += __shfl_xor(v, 4);
                v += __shfl_xor(v, 8);
                if (lr == 0) {
                    const int gr = m0 + wm + mf * 16 + lk * 4 + rr;
                    atomicAdd(&rowsum[(size_t)z * T + gr], v);
                }
            }
    } else {
        float* Op = out + (size_t)z * T * C;
        const float* rs = rowsum + (size_t)z * T;
#pragma unroll
        for (int mf = 0; mf < 4; ++mf)
#pragma unroll
            for (int rr = 0; rr < 4; ++rr) {
                const int gr = m0 + wm + mf * 16 + lk * 4 + rr;
                const float inv = 1.0f / rs[gr];
#pragma unroll
                for (int nf = 0; nf < 4; ++nf) {
                    const int gc = n0 + wn + nf * 16 + lr;
                    Op[(size_t)gr * C + gc] = acc[mf][nf][rr] * inv;
                }
            }
    }
}

// ---- fused fp32 -> bf16 convert for x, Wk, Wq, Wv + rowsum zeroing ----
__global__ __launch_bounds__(256) void cvt_all(
    const float* __restrict__ x, const float* __restrict__ Wk,
    const float* __restrict__ Wq, const float* __restrict__ Wv,
    ushort* __restrict__ xb, ushort* __restrict__ Wcat,
    float* __restrict__ rowsum) {
    constexpr int C = 1024;
    constexpr int NX = 8388608 / 8, NW = C * C / 8;
    if (blockIdx.x >= 5632) {   // last 8 blocks: zero rowsum (8192 floats)
        const int idx = (blockIdx.x - 5632) * 256 + threadIdx.x;  // 0..2047
        float4 zz = {0.f, 0.f, 0.f, 0.f};
        reinterpret_cast<float4*>(rowsum)[idx] = zz;
        return;
    }
    int i = blockIdx.x * 256 + threadIdx.x;
    const float* src; ushort* dst;
    if (i < NX)               { src = x;  dst = xb; }
    else if (i < NX + NW)     { src = Wk; dst = Wcat;                 i -= NX; }
    else if (i < NX + 2 * NW) { src = Wq; dst = Wcat + (size_t)C * C; i -= NX + NW; }
    else                      { src = Wv; dst = Wcat + 2 * (size_t)C * C; i -= NX + 2 * NW; }
    const float4* p = reinterpret_cast<const float4*>(src) + (size_t)i * 2;
    float4 a = p[0], b = p[1];
    ushort o[8] = {f2b(a.x), f2b(a.y), f2b(a.z), f2b(a.w),
                   f2b(b.x), f2b(b.y), f2b(b.z), f2b(b.w)};
    reinterpret_cast<uint4*>(dst)[i] = *reinterpret_cast<uint4*>(o);
}

extern "C" void kernel_launch(void* const* d_in, const int* in_sizes, int n_in,
                              void* d_out, int out_size, void* d_ws, size_t ws_size,
                              hipStream_t stream) {
    const float* x  = (const float*)d_in[0];
    const float* Wk = (const float*)d_in[1];
    const float* bk = (const float*)d_in[2];
    const float* Wq = (const float*)d_in[3];
    const float* bq = (const float*)d_in[4];
    const float* Wv = (const float*)d_in[5];
    const float* bv = (const float*)d_in[6];
    float* out = (float*)d_out;

    constexpr int B = 4, T = 2048, C = 1024;
    constexpr size_t BTC = (size_t)B * T * C;  // 8388608

    ushort* Kb = (ushort*)d_ws;
    ushort* Qb = Kb + BTC;
    ushort* Vt = Qb + BTC;                      // V stored transposed [B][C][T]
    ushort* Sb = Vt + BTC;                      // B*T*T ushorts (holds P' = exp)
    float* rowsum = (float*)(Sb + (size_t)B * T * T);  // B*T floats
    ushort* xb   = Sb;                          // aliased (dead before scores)
    ushort* Wcat = Sb + BTC;

    dim3 blk(256);

    // 0) fp32 -> bf16 + rowsum zeroing (single fused launch)
    cvt_all<<<dim3(5640), blk, 0, stream>>>(x, Wk, Wq, Wv, xb, Wcat, rowsum);

    // 1) fused QKV projection (128x192 tiles, ring-3, 2 blocks/CU, exact 2 rounds)
    qkv_gemm<<<dim3(1024), dim3(512), 0, stream>>>(xb, Wcat, bk, bq, bv, Kb, Qb, Vt);

    // 2) scores -> P' = exp(s/32) + row-sums (lower-triangle blocks only)
    gemm_ring<1><<<dim3(544), blk, 0, stream>>>(Kb, Qb, Vt, Sb, rowsum, out);

    // 3) y = (P' @ V) / rowsum  (normalization via precomputed row-sums)
    gemm_ring<2><<<dim3(512), blk, 0, stream>>>(Kb, Qb, Vt, Sb, rowsum, out);
}

// Round 12
// 140.663 us; speedup vs baseline: 1.0220x; 1.0220x over previous
//
#include <hip/hip_runtime.h>
#include <hip/hip_bf16.h>

typedef __attribute__((ext_vector_type(8))) short short8;
typedef __attribute__((ext_vector_type(4))) float f32x4;

// ---------------- helpers ----------------
__device__ __forceinline__ ushort f2b(float f) {
    __hip_bfloat16 h = __float2bfloat16(f);
    return *reinterpret_cast<ushort*>(&h);
}
__device__ __forceinline__ float b2f(ushort u) {
    return __uint_as_float(((unsigned)u) << 16);
}
__device__ __forceinline__ void gload16(const ushort* g, ushort* l) {
    __builtin_amdgcn_global_load_lds(
        (const __attribute__((address_space(1))) void*)g,
        (__attribute__((address_space(3))) void*)l, 16, 0, 0);
}

// ============================================================================
// QKV: 256x128-tile NT GEMM, BK=32, 3-slot LDS ring (72 KB -> 2 blocks/CU),
// single barrier per K-tile, depth-2 prefetch, counted vmcnt.
// EXACT r9 structure (measured 63.6 us — best of 5 tile geometries tried).
// ============================================================================
__global__ __launch_bounds__(512, 4) void qkv_gemm256(
    const ushort* __restrict__ xb, const ushort* __restrict__ Wcat,
    const float* __restrict__ bk, const float* __restrict__ bq, const float* __restrict__ bv,
    ushort* __restrict__ Kb, ushort* __restrict__ Qb, ushort* __restrict__ Vt) {
    constexpr int T = 2048, C = 1024, K = 1024, NT = 32;
    __shared__ ushort smem[36864];  // 72 KB

    const int tid = threadIdx.x;
    const int l = tid & 63, w = tid >> 6;
    const int wm = (w >> 1) * 64, wn = (w & 1) * 64;   // 4M x 2N, 64x64/wave
    const int lr = l & 15, lk = l >> 4;

    const int b = blockIdx.x;                  // 768 = 8*96
    const int wg = (b & 7) * 96 + (b >> 3);    // XCD-bijective
    const int m0 = (wg / 24) * 256, n0 = (wg % 24) * 128;

    const int srow = w * 16 + (l >> 2);                      // 0..127
    const int scb = ((l & 3) << 4) ^ ((l & 32) ? 32 : 0);    // swizzled byte col
    const ushort* gA = xb + (size_t)(m0 + srow) * K + (scb >> 1);
    const ushort* gB = Wcat + (size_t)(n0 + srow) * K + (scb >> 1);

    const int LB = lr * 32 + ((lk << 3) ^ ((lr >= 8) ? 16 : 0));

    f32x4 acc[4][4] = {};

#define STAGEQ(tt, sl)                                                    \
    {                                                                     \
        const int _ko = (tt) * 32;                                        \
        ushort* _s = smem + (sl) * 12288 + w * 512;                       \
        gload16(gA + _ko,                   _s);                          \
        gload16(gA + (size_t)128 * K + _ko, _s + 4096);                   \
        gload16(gB + _ko,                   _s + 8192);                   \
    }

    STAGEQ(0, 0);
    STAGEQ(1, 1);
    asm volatile("s_waitcnt vmcnt(3)" ::: "memory");
    __builtin_amdgcn_s_barrier();
    asm volatile("" ::: "memory");

    int sc = 0, ss = 2;
    for (int t = 0; t < NT; ++t) {
        const ushort* slot = smem + sc * 12288;
        const ushort* Ab = slot + (wm >> 4) * 512 + LB;
        const ushort* Bb = slot + 8192 + (wn >> 4) * 512 + LB;
        short8 af[4], bf4[4];
#pragma unroll
        for (int f = 0; f < 4; ++f) af[f] = *reinterpret_cast<const short8*>(Ab + f * 512);
#pragma unroll
        for (int g = 0; g < 4; ++g) bf4[g] = *reinterpret_cast<const short8*>(Bb + g * 512);
        if (t + 2 < NT) STAGEQ(t + 2, ss);
        __builtin_amdgcn_s_setprio(1);
#pragma unroll
        for (int f = 0; f < 4; ++f)
#pragma unroll
            for (int g = 0; g < 4; ++g)
                acc[f][g] = __builtin_amdgcn_mfma_f32_16x16x32_bf16(af[f], bf4[g], acc[f][g], 0, 0, 0);
        __builtin_amdgcn_s_setprio(0);
        if (t + 1 < NT) {
            if (t + 2 < NT) asm volatile("s_waitcnt vmcnt(3)" ::: "memory");
            else            asm volatile("s_waitcnt vmcnt(0)" ::: "memory");
            __builtin_amdgcn_s_barrier();
            asm volatile("" ::: "memory");
        }
        sc = (sc == 2) ? 0 : sc + 1;
        ss = (ss == 2) ? 0 : ss + 1;
    }
#undef STAGEQ

    const int zsel = n0 >> 10;
    const int c0 = (n0 & 1023) + wn;
    if (zsel < 2) {
        ushort* O = (zsel == 0) ? Kb : Qb;
        const float* bias = (zsel == 0) ? bk : bq;
#pragma unroll
        for (int f = 0; f < 4; ++f)
#pragma unroll
            for (int g = 0; g < 4; ++g) {
                const int gc = c0 + g * 16 + lr;
                const float badd = bias[gc];
#pragma unroll
                for (int rr = 0; rr < 4; ++rr) {
                    const int gr = m0 + wm + f * 16 + lk * 4 + rr;
                    O[(size_t)gr * C + gc] = f2b(acc[f][g][rr] + badd);
                }
            }
    } else {
        const int zb = (m0 + wm) >> 11;
        const int s0 = (m0 + wm) & 2047;
        ushort* Vz = Vt + (size_t)zb * C * T;
#pragma unroll
        for (int f = 0; f < 4; ++f)
#pragma unroll
            for (int g = 0; g < 4; ++g) {
                const int gc = c0 + g * 16 + lr;
                const float badd = bv[gc];
                const int s = s0 + f * 16 + lk * 4;
                ushort tmp[4];
#pragma unroll
                for (int rr = 0; rr < 4; ++rr) tmp[rr] = f2b(acc[f][g][rr] + badd);
                *reinterpret_cast<uint2*>(Vz + (size_t)gc * T + s) =
                    *reinterpret_cast<uint2*>(tmp);
            }
    }
}

// ============================================================================
// 3-slot ring 128x128 NT GEMM for scores / PV.
// MODE 1 = scores: writes p' = exp(s/32) (0 above diag in diag blocks) and
//          stores per-block partial row-sums to part[z][i][j][half][128]
//          (half = wn>>6 — the two waves covering different column halves
//          get separate slots; NO shared writers -> no atomics, no race).
// MODE 2 = PV: plain GEMM (no ones-MFMA); post-loop gather sums partials
//          (both halves, j=0..i) into LDS reciprocals; y = acc * inv[row].
// ============================================================================
template <int MODE>
__global__ __launch_bounds__(256, 3) void gemm_ring(
    const ushort* __restrict__ Kb, const ushort* __restrict__ Qb,
    const ushort* __restrict__ Vt, ushort* __restrict__ Sb,
    float* __restrict__ part, float* __restrict__ out) {
    constexpr int T = 2048, C = 1024;
    __shared__ ushort smem[24576];  // 48 KB

    const int tid = threadIdx.x;
    const int l = tid & 63, w = tid >> 6;
    const int wm = (w >> 1) * 64, wn = (w & 1) * 64;
    const int lr = l & 15, lk = l >> 4;

    int m0, n0, nt, iblk = 0, jblk = 0, z = 0;
    const ushort *Au, *Bu;
    int ldA, ldB;
    if constexpr (MODE == 1) {
        const int wg0 = blockIdx.x;                  // 544 = 8*68
        const int wg = (wg0 & 7) * 68 + (wg0 >> 3);
        z = wg / 136; const int t136 = wg % 136;
        int i = (int)((sqrtf(8.f * t136 + 1.f) - 1.f) * 0.5f);
        while ((i + 1) * (i + 2) / 2 <= t136) ++i;
        while (i * (i + 1) / 2 > t136) --i;
        const int j = t136 - i * (i + 1) / 2;
        iblk = i; jblk = j;
        m0 = i * 128; n0 = j * 128;
        Au = Qb + (size_t)z * T * C + (size_t)m0 * C; ldA = C;
        Bu = Kb + (size_t)z * T * C + (size_t)n0 * C; ldB = C;
        nt = 32;
    } else {
        const int wg0 = blockIdx.x;                  // 512 = 8*64
        const int wg = (wg0 & 7) * 64 + (wg0 >> 3);
        const int half = wg >> 8, s2 = wg & 255;
        z = s2 >> 6; const int r6 = s2 & 63;
        const int nb = r6 & 7, ii = r6 >> 3;
        const int i = half ? (15 - ii) : ii;
        iblk = i;
        m0 = i * 128; n0 = nb * 128;
        Au = Sb + (size_t)z * T * T + (size_t)m0 * T; ldA = T;
        Bu = Vt + (size_t)z * C * T + (size_t)n0 * T; ldB = T;
        nt = 4 * (i + 1);
    }

    const int srow = w * 16 + (l >> 2);
    const int scb = ((l & 3) << 4) ^ ((l >= 32) ? 32 : 0);
    const ushort* gA = Au + (size_t)srow * ldA + (scb >> 1);
    const ushort* gB = Bu + (size_t)srow * ldB + (scb >> 1);
    const size_t a64 = (size_t)64 * ldA, b64 = (size_t)64 * ldB;
    const int LBu = lr * 32 + ((lk << 3) ^ ((lr >= 8) ? 16 : 0));

    f32x4 acc[4][4] = {};

#define STAGE(tt, sl)                                                    \
    {                                                                    \
        const int _ko = (tt) * 32;                                       \
        ushort* _d = smem + (sl) * 8192 + w * 512;                       \
        gload16(gA + _ko,        _d);                                    \
        gload16(gA + a64 + _ko,  _d + 2048);                             \
        gload16(gB + _ko,        _d + 4096);                             \
        gload16(gB + b64 + _ko,  _d + 6144);                             \
    }

    STAGE(0, 0);
    STAGE(1, 1);
    asm volatile("s_waitcnt vmcnt(4)" ::: "memory");
    __builtin_amdgcn_s_barrier();
    asm volatile("" ::: "memory");

    int sc = 0, ss = 2;
    for (int t = 0; t < nt; ++t) {
        const ushort* As = smem + sc * 8192 + (wm >> 4) * 512 + LBu;
        const ushort* Bs = smem + sc * 8192 + 4096 + (wn >> 4) * 512 + LBu;
        short8 af[4], bf[4];
#pragma unroll
        for (int q = 0; q < 4; ++q) {
            af[q] = *reinterpret_cast<const short8*>(As + q * 512);
            bf[q] = *reinterpret_cast<const short8*>(Bs + q * 512);
        }
        if (t + 2 < nt) STAGE(t + 2, ss);
        __builtin_amdgcn_s_setprio(1);
#pragma unroll
        for (int mf = 0; mf < 4; ++mf)
#pragma unroll
            for (int nf = 0; nf < 4; ++nf)
                acc[mf][nf] = __builtin_amdgcn_mfma_f32_16x16x32_bf16(af[mf], bf[nf], acc[mf][nf], 0, 0, 0);
        __builtin_amdgcn_s_setprio(0);
        if (t + 1 < nt) {
            if (t + 2 < nt) asm volatile("s_waitcnt vmcnt(4)" ::: "memory");
            else            asm volatile("s_waitcnt vmcnt(0)" ::: "memory");
            __builtin_amdgcn_s_barrier();
            asm volatile("" ::: "memory");
        }
        sc = (sc == 2) ? 0 : sc + 1;
        ss = (ss == 2) ? 0 : ss + 1;
    }
#undef STAGE

    if constexpr (MODE == 1) {
        // write p' = exp(s/32) (0 above diag) + per-block partial row-sums
        ushort* Sp = Sb + (size_t)z * T * T;
        const bool diag = (iblk == jblk);
        float rp[4][4];
#pragma unroll
        for (int mf = 0; mf < 4; ++mf)
#pragma unroll
            for (int rr = 0; rr < 4; ++rr) rp[mf][rr] = 0.f;
#pragma unroll
        for (int mf = 0; mf < 4; ++mf)
#pragma unroll
            for (int nf = 0; nf < 4; ++nf) {
                const int gc = n0 + wn + nf * 16 + lr;
#pragma unroll
                for (int rr = 0; rr < 4; ++rr) {
                    const int gr = m0 + wm + mf * 16 + lk * 4 + rr;
                    float p = __expf(acc[mf][nf][rr] * 0.03125f);
                    if (diag && gc > gr) p = 0.f;
                    const ushort us = f2b(p);
                    Sp[(size_t)gr * T + gc] = us;
                    rp[mf][rr] += b2f(us);   // rounded value: matches PV numerator
                }
            }
        // reduce over 16 lanes sharing each row; per-wave-half slot (no race:
        // waves w=0,1 share rows wm=0 but differ in wn>>6; same for w=2,3)
        float* pb = part + ((((size_t)z * 16 + iblk) * 16 + jblk) * 2 + (wn >> 6)) * 128;
#pragma unroll
        for (int mf = 0; mf < 4; ++mf)
#pragma unroll
            for (int rr = 0; rr < 4; ++rr) {
                float v = rp[mf][rr];
                v += __shfl_xor(v, 1);
                v += __shfl_xor(v, 2);
                v += __shfl_xor(v, 4);
                v += __shfl_xor(v, 8);
                if (lr == 0) pb[wm + mf * 16 + lk * 4 + rr] = v;
            }
    } else {
        // gather partial row-sums (both halves, j=0..iblk) -> LDS reciprocals
        __syncthreads();
        float* smem_f = reinterpret_cast<float*>(smem);
        if (tid < 128) {
            const float* pb = part + (((size_t)z * 16 + iblk) * 16) * 2 * 128 + tid;
            float s = 0.f;
            for (int j = 0; j <= iblk; ++j)
                s += pb[(size_t)j * 256] + pb[(size_t)j * 256 + 128];
            smem_f[tid] = 1.0f / s;
        }
        __syncthreads();
        float* Op = out + (size_t)z * T * C;
#pragma unroll
        for (int mf = 0; mf < 4; ++mf)
#pragma unroll
            for (int rr = 0; rr < 4; ++rr) {
                const int lrow = wm + mf * 16 + lk * 4 + rr;
                const float inv = smem_f[lrow];
#pragma unroll
                for (int nf = 0; nf < 4; ++nf) {
                    const int gc = n0 + wn + nf * 16 + lr;
                    Op[(size_t)(m0 + lrow) * C + gc] = acc[mf][nf][rr] * inv;
                }
            }
    }
}

// ---- fused fp32 -> bf16 convert for x, Wk, Wq, Wv ----
__global__ __launch_bounds__(256) void cvt_all(
    const float* __restrict__ x, const float* __restrict__ Wk,
    const float* __restrict__ Wq, const float* __restrict__ Wv,
    ushort* __restrict__ xb, ushort* __restrict__ Wcat) {
    constexpr int C = 1024;
    constexpr int NX = 8388608 / 8, NW = C * C / 8;
    int i = blockIdx.x * 256 + threadIdx.x;
    const float* src; ushort* dst;
    if (i < NX)               { src = x;  dst = xb; }
    else if (i < NX + NW)     { src = Wk; dst = Wcat;                 i -= NX; }
    else if (i < NX + 2 * NW) { src = Wq; dst = Wcat + (size_t)C * C; i -= NX + NW; }
    else                      { src = Wv; dst = Wcat + 2 * (size_t)C * C; i -= NX + 2 * NW; }
    const float4* p = reinterpret_cast<const float4*>(src) + (size_t)i * 2;
    float4 a = p[0], b = p[1];
    ushort o[8] = {f2b(a.x), f2b(a.y), f2b(a.z), f2b(a.w),
                   f2b(b.x), f2b(b.y), f2b(b.z), f2b(b.w)};
    reinterpret_cast<uint4*>(dst)[i] = *reinterpret_cast<uint4*>(o);
}

extern "C" void kernel_launch(void* const* d_in, const int* in_sizes, int n_in,
                              void* d_out, int out_size, void* d_ws, size_t ws_size,
                              hipStream_t stream) {
    const float* x  = (const float*)d_in[0];
    const float* Wk = (const float*)d_in[1];
    const float* bk = (const float*)d_in[2];
    const float* Wq = (const float*)d_in[3];
    const float* bq = (const float*)d_in[4];
    const float* Wv = (const float*)d_in[5];
    const float* bv = (const float*)d_in[6];
    float* out = (float*)d_out;

    constexpr int B = 4, T = 2048, C = 1024;
    constexpr size_t BTC = (size_t)B * T * C;  // 8388608

    ushort* Kb = (ushort*)d_ws;
    ushort* Qb = Kb + BTC;
    ushort* Vt = Qb + BTC;                      // V stored transposed [B][C][T]
    ushort* Sb = Vt + BTC;                      // B*T*T ushorts (holds P' = exp)
    float* part = (float*)(Sb + (size_t)B * T * T);  // [B][16][16][2][128] partials
    ushort* xb   = Sb;                          // aliased (dead before scores)
    ushort* Wcat = Sb + BTC;

    dim3 blk(256);

    // 0) fp32 -> bf16 (single fused launch)
    cvt_all<<<dim3(5632), blk, 0, stream>>>(x, Wk, Wq, Wv, xb, Wcat);

    // 1) fused QKV projection (256x128, BK=32 ring-3, 2 blocks/CU) — r9 exact
    qkv_gemm256<<<dim3(768), dim3(512), 0, stream>>>(xb, Wcat, bk, bq, bv, Kb, Qb, Vt);

    // 2) scores -> P' = exp(s/32) + partial row-sums (lower-triangle blocks)
    gemm_ring<1><<<dim3(544), blk, 0, stream>>>(Kb, Qb, Vt, Sb, part, out);

    // 3) y = (P' @ V) * (1/rowsum)  (partials gathered per block, no ones-MFMA)
    gemm_ring<2><<<dim3(512), blk, 0, stream>>>(Kb, Qb, Vt, Sb, part, out);
}

// Round 13
// 137.148 us; speedup vs baseline: 1.0482x; 1.0256x over previous
//
#include <hip/hip_runtime.h>
#include <hip/hip_bf16.h>

typedef __attribute__((ext_vector_type(8))) short short8;
typedef __attribute__((ext_vector_type(4))) float f32x4;

// ---------------- helpers ----------------
__device__ __forceinline__ ushort f2b(float f) {
    __hip_bfloat16 h = __float2bfloat16(f);
    return *reinterpret_cast<ushort*>(&h);
}
__device__ __forceinline__ float b2f(ushort u) {
    return __uint_as_float(((unsigned)u) << 16);
}
__device__ __forceinline__ void gload16(const ushort* g, ushort* l) {
    __builtin_amdgcn_global_load_lds(
        (const __attribute__((address_space(1))) void*)g,
        (__attribute__((address_space(3))) void*)l, 16, 0, 0);
}

// ============================================================================
// QKV: 256x128-tile NT GEMM, BK=32, 3-slot LDS ring (72 KB -> 2 blocks/CU),
// single barrier per K-tile, depth-2 prefetch, counted vmcnt.
// Best of 5 measured tile geometries (63.6 us / ~810 TF).
// ============================================================================
__global__ __launch_bounds__(512, 4) void qkv_gemm256(
    const ushort* __restrict__ xb, const ushort* __restrict__ Wcat,
    const float* __restrict__ bk, const float* __restrict__ bq, const float* __restrict__ bv,
    ushort* __restrict__ Kb, ushort* __restrict__ Qb, ushort* __restrict__ Vt) {
    constexpr int T = 2048, C = 1024, K = 1024, NT = 32;
    __shared__ ushort smem[36864];  // 72 KB = 3 slots x 12288 ushorts (24 KB)

    const int tid = threadIdx.x;
    const int l = tid & 63, w = tid >> 6;
    const int wm = (w >> 1) * 64, wn = (w & 1) * 64;   // 4M x 2N, 64x64/wave
    const int lr = l & 15, lk = l >> 4;

    const int b = blockIdx.x;                  // 768 = 8*96
    const int wg = (b & 7) * 96 + (b >> 3);    // XCD-bijective
    const int m0 = (wg / 24) * 256, n0 = (wg % 24) * 128;

    const int srow = w * 16 + (l >> 2);                      // 0..127
    const int scb = ((l & 3) << 4) ^ ((l & 32) ? 32 : 0);    // swizzled byte col
    const ushort* gA = xb + (size_t)(m0 + srow) * K + (scb >> 1);
    const ushort* gB = Wcat + (size_t)(n0 + srow) * K + (scb >> 1);

    const int LB = lr * 32 + ((lk << 3) ^ ((lr >= 8) ? 16 : 0));

    f32x4 acc[4][4] = {};

#define STAGEQ(tt, sl)                                                    \
    {                                                                     \
        const int _ko = (tt) * 32;                                        \
        ushort* _s = smem + (sl) * 12288 + w * 512;                       \
        gload16(gA + _ko,                   _s);                          \
        gload16(gA + (size_t)128 * K + _ko, _s + 4096);                   \
        gload16(gB + _ko,                   _s + 8192);                   \
    }

    STAGEQ(0, 0);
    STAGEQ(1, 1);
    asm volatile("s_waitcnt vmcnt(3)" ::: "memory");
    __builtin_amdgcn_s_barrier();
    asm volatile("" ::: "memory");

    int sc = 0, ss = 2;
    for (int t = 0; t < NT; ++t) {
        const ushort* slot = smem + sc * 12288;
        const ushort* Ab = slot + (wm >> 4) * 512 + LB;
        const ushort* Bb = slot + 8192 + (wn >> 4) * 512 + LB;
        short8 af[4], bf4[4];
#pragma unroll
        for (int f = 0; f < 4; ++f) af[f] = *reinterpret_cast<const short8*>(Ab + f * 512);
#pragma unroll
        for (int g = 0; g < 4; ++g) bf4[g] = *reinterpret_cast<const short8*>(Bb + g * 512);
        if (t + 2 < NT) STAGEQ(t + 2, ss);
        __builtin_amdgcn_s_setprio(1);
#pragma unroll
        for (int f = 0; f < 4; ++f)
#pragma unroll
            for (int g = 0; g < 4; ++g)
                acc[f][g] = __builtin_amdgcn_mfma_f32_16x16x32_bf16(af[f], bf4[g], acc[f][g], 0, 0, 0);
        __builtin_amdgcn_s_setprio(0);
        if (t + 1 < NT) {
            if (t + 2 < NT) asm volatile("s_waitcnt vmcnt(3)" ::: "memory");
            else            asm volatile("s_waitcnt vmcnt(0)" ::: "memory");
            __builtin_amdgcn_s_barrier();
            asm volatile("" ::: "memory");
        }
        sc = (sc == 2) ? 0 : sc + 1;
        ss = (ss == 2) ? 0 : ss + 1;
    }
#undef STAGEQ

    const int zsel = n0 >> 10;
    const int c0 = (n0 & 1023) + wn;
    if (zsel < 2) {
        ushort* O = (zsel == 0) ? Kb : Qb;
        const float* bias = (zsel == 0) ? bk : bq;
#pragma unroll
        for (int f = 0; f < 4; ++f)
#pragma unroll
            for (int g = 0; g < 4; ++g) {
                const int gc = c0 + g * 16 + lr;
                const float badd = bias[gc];
#pragma unroll
                for (int rr = 0; rr < 4; ++rr) {
                    const int gr = m0 + wm + f * 16 + lk * 4 + rr;
                    O[(size_t)gr * C + gc] = f2b(acc[f][g][rr] + badd);
                }
            }
    } else {
        const int zb = (m0 + wm) >> 11;
        const int s0 = (m0 + wm) & 2047;
        ushort* Vz = Vt + (size_t)zb * C * T;
#pragma unroll
        for (int f = 0; f < 4; ++f)
#pragma unroll
            for (int g = 0; g < 4; ++g) {
                const int gc = c0 + g * 16 + lr;
                const float badd = bv[gc];
                const int s = s0 + f * 16 + lk * 4;
                ushort tmp[4];
#pragma unroll
                for (int rr = 0; rr < 4; ++rr) tmp[rr] = f2b(acc[f][g][rr] + badd);
                *reinterpret_cast<uint2*>(Vz + (size_t)gc * T + s) =
                    *reinterpret_cast<uint2*>(tmp);
            }
    }
}

// ============================================================================
// 3-slot ring 128x128 NT GEMM for scores / PV.
// MODE 1 = scores: writes p' = exp(s/32) (0 above diag in diag blocks).
// MODE 2 = PV: ones-column MFMA row-sums; epilogue y = acc / rowsum.
// ============================================================================
template <int MODE>
__global__ __launch_bounds__(256, 3) void gemm_ring(
    const ushort* __restrict__ Kb, const ushort* __restrict__ Qb,
    const ushort* __restrict__ Vt, ushort* __restrict__ Sb, float* __restrict__ out) {
    constexpr int T = 2048, C = 1024;
    __shared__ ushort smem[24576];  // 48 KB

    const int tid = threadIdx.x;
    const int l = tid & 63, w = tid >> 6;
    const int wm = (w >> 1) * 64, wn = (w & 1) * 64;
    const int lr = l & 15, lk = l >> 4;

    int m0, n0, nt, iblk = 0, jblk = 0, z = 0;
    const ushort *Au, *Bu;
    int ldA, ldB;
    if constexpr (MODE == 1) {
        const int wg0 = blockIdx.x;                  // 544 = 8*68
        const int wg = (wg0 & 7) * 68 + (wg0 >> 3);
        z = wg / 136; const int t136 = wg % 136;
        int i = (int)((sqrtf(8.f * t136 + 1.f) - 1.f) * 0.5f);
        while ((i + 1) * (i + 2) / 2 <= t136) ++i;
        while (i * (i + 1) / 2 > t136) --i;
        const int j = t136 - i * (i + 1) / 2;
        iblk = i; jblk = j;
        m0 = i * 128; n0 = j * 128;
        Au = Qb + (size_t)z * T * C + (size_t)m0 * C; ldA = C;
        Bu = Kb + (size_t)z * T * C + (size_t)n0 * C; ldB = C;
        nt = 32;
    } else {
        const int wg0 = blockIdx.x;                  // 512 = 8*64
        const int wg = (wg0 & 7) * 64 + (wg0 >> 3);
        const int half = wg >> 8, s2 = wg & 255;
        z = s2 >> 6; const int r6 = s2 & 63;
        const int nb = r6 & 7, ii = r6 >> 3;
        const int i = half ? (15 - ii) : ii;
        iblk = i;
        m0 = i * 128; n0 = nb * 128;
        Au = Sb + (size_t)z * T * T + (size_t)m0 * T; ldA = T;
        Bu = Vt + (size_t)z * C * T + (size_t)n0 * T; ldB = T;
        nt = 4 * (i + 1);
    }

    const int srow = w * 16 + (l >> 2);
    const int scb = ((l & 3) << 4) ^ ((l >= 32) ? 32 : 0);
    const ushort* gA = Au + (size_t)srow * ldA + (scb >> 1);
    const ushort* gB = Bu + (size_t)srow * ldB + (scb >> 1);
    const size_t a64 = (size_t)64 * ldA, b64 = (size_t)64 * ldB;
    const int LBu = lr * 32 + ((lk << 3) ^ ((lr >= 8) ? 16 : 0));

    f32x4 acc[4][4] = {};
    f32x4 acc1[4] = {};
    short8 ones;
#pragma unroll
    for (int q = 0; q < 8; ++q) ones[q] = (short)0x3F80;  // bf16 1.0

#define STAGE(tt, sl)                                                    \
    {                                                                    \
        const int _ko = (tt) * 32;                                       \
        ushort* _d = smem + (sl) * 8192 + w * 512;                       \
        gload16(gA + _ko,        _d);                                    \
        gload16(gA + a64 + _ko,  _d + 2048);                             \
        gload16(gB + _ko,        _d + 4096);                             \
        gload16(gB + b64 + _ko,  _d + 6144);                             \
    }

    STAGE(0, 0);
    STAGE(1, 1);
    asm volatile("s_waitcnt vmcnt(4)" ::: "memory");
    __builtin_amdgcn_s_barrier();
    asm volatile("" ::: "memory");

    int sc = 0, ss = 2;
    for (int t = 0; t < nt; ++t) {
        const ushort* As = smem + sc * 8192 + (wm >> 4) * 512 + LBu;
        const ushort* Bs = smem + sc * 8192 + 4096 + (wn >> 4) * 512 + LBu;
        short8 af[4], bf[4];
#pragma unroll
        for (int q = 0; q < 4; ++q) {
            af[q] = *reinterpret_cast<const short8*>(As + q * 512);
            bf[q] = *reinterpret_cast<const short8*>(Bs + q * 512);
        }
        if (t + 2 < nt) STAGE(t + 2, ss);
        __builtin_amdgcn_s_setprio(1);
#pragma unroll
        for (int mf = 0; mf < 4; ++mf)
#pragma unroll
            for (int nf = 0; nf < 4; ++nf)
                acc[mf][nf] = __builtin_amdgcn_mfma_f32_16x16x32_bf16(af[mf], bf[nf], acc[mf][nf], 0, 0, 0);
        if constexpr (MODE == 2) {
#pragma unroll
            for (int mf = 0; mf < 4; ++mf)
                acc1[mf] = __builtin_amdgcn_mfma_f32_16x16x32_bf16(af[mf], ones, acc1[mf], 0, 0, 0);
        }
        __builtin_amdgcn_s_setprio(0);
        if (t + 1 < nt) {
            if (t + 2 < nt) asm volatile("s_waitcnt vmcnt(4)" ::: "memory");
            else            asm volatile("s_waitcnt vmcnt(0)" ::: "memory");
            __builtin_amdgcn_s_barrier();
            asm volatile("" ::: "memory");
        }
        sc = (sc == 2) ? 0 : sc + 1;
        ss = (ss == 2) ? 0 : ss + 1;
    }
#undef STAGE

    if constexpr (MODE == 1) {
        ushort* Sp = Sb + (size_t)z * T * T;
        const bool diag = (iblk == jblk);
#pragma unroll
        for (int mf = 0; mf < 4; ++mf)
#pragma unroll
            for (int nf = 0; nf < 4; ++nf) {
                const int gc = n0 + wn + nf * 16 + lr;
#pragma unroll
                for (int rr = 0; rr < 4; ++rr) {
                    const int gr = m0 + wm + mf * 16 + lk * 4 + rr;
                    float p = __expf(acc[mf][nf][rr] * 0.03125f);
                    if (diag && gc > gr) p = 0.f;
                    Sp[(size_t)gr * T + gc] = f2b(p);
                }
            }
    } else {
        float* Op = out + (size_t)z * T * C;
#pragma unroll
        for (int mf = 0; mf < 4; ++mf)
#pragma unroll
            for (int rr = 0; rr < 4; ++rr) {
                const int gr = m0 + wm + mf * 16 + lk * 4 + rr;
                const float inv = 1.0f / acc1[mf][rr];
#pragma unroll
                for (int nf = 0; nf < 4; ++nf) {
                    const int gc = n0 + wn + nf * 16 + lr;
                    Op[(size_t)gr * C + gc] = acc[mf][nf][rr] * inv;
                }
            }
    }
}

// ---- fused fp32 -> bf16 convert for x, Wk, Wq, Wv ----
__global__ __launch_bounds__(256) void cvt_all(
    const float* __restrict__ x, const float* __restrict__ Wk,
    const float* __restrict__ Wq, const float* __restrict__ Wv,
    ushort* __restrict__ xb, ushort* __restrict__ Wcat) {
    constexpr int C = 1024;
    constexpr int NX = 8388608 / 8, NW = C * C / 8;
    int i = blockIdx.x * 256 + threadIdx.x;
    const float* src; ushort* dst;
    if (i < NX)               { src = x;  dst = xb; }
    else if (i < NX + NW)     { src = Wk; dst = Wcat;                 i -= NX; }
    else if (i < NX + 2 * NW) { src = Wq; dst = Wcat + (size_t)C * C; i -= NX + NW; }
    else                      { src = Wv; dst = Wcat + 2 * (size_t)C * C; i -= NX + 2 * NW; }
    const float4* p = reinterpret_cast<const float4*>(src) + (size_t)i * 2;
    float4 a = p[0], b = p[1];
    ushort o[8] = {f2b(a.x), f2b(a.y), f2b(a.z), f2b(a.w),
                   f2b(b.x), f2b(b.y), f2b(b.z), f2b(b.w)};
    reinterpret_cast<uint4*>(dst)[i] = *reinterpret_cast<uint4*>(o);
}

extern "C" void kernel_launch(void* const* d_in, const int* in_sizes, int n_in,
                              void* d_out, int out_size, void* d_ws, size_t ws_size,
                              hipStream_t stream) {
    const float* x  = (const float*)d_in[0];
    const float* Wk = (const float*)d_in[1];
    const float* bk = (const float*)d_in[2];
    const float* Wq = (const float*)d_in[3];
    const float* bq = (const float*)d_in[4];
    const float* Wv = (const float*)d_in[5];
    const float* bv = (const float*)d_in[6];
    float* out = (float*)d_out;

    constexpr int B = 4, T = 2048, C = 1024;
    constexpr size_t BTC = (size_t)B * T * C;  // 8388608

    ushort* Kb = (ushort*)d_ws;
    ushort* Qb = Kb + BTC;
    ushort* Vt = Qb + BTC;                      // V stored transposed [B][C][T]
    ushort* Sb = Vt + BTC;                      // B*T*T ushorts (holds P' = exp)
    ushort* xb   = Sb;                          // aliased (dead before scores)
    ushort* Wcat = Sb + BTC;

    dim3 blk(256);

    // 0) fp32 -> bf16 (single fused launch)
    cvt_all<<<dim3(5632), blk, 0, stream>>>(x, Wk, Wq, Wv, xb, Wcat);

    // 1) fused QKV projection (256x128, BK=32 ring-3, 2 blocks/CU)
    qkv_gemm256<<<dim3(768), dim3(512), 0, stream>>>(xb, Wcat, bk, bq, bv, Kb, Qb, Vt);

    // 2) scores -> P' = exp(s/32), causal (lower-triangle blocks; full diag tiles)
    gemm_ring<1><<<dim3(544), blk, 0, stream>>>(Kb, Qb, Vt, Sb, out);

    // 3) y = (P' @ V) / rowsum(P')  -- softmax normalization fused via ones-MFMA
    gemm_ring<2><<<dim3(512), blk, 0, stream>>>(Kb, Qb, Vt, Sb, out);
}

// Round 14
// 126.449 us; speedup vs baseline: 1.1369x; 1.0846x over previous
//
#include <hip/hip_runtime.h>
#include <hip/hip_bf16.h>

typedef __attribute__((ext_vector_type(8))) short short8;
typedef __attribute__((ext_vector_type(4))) float f32x4;

// ---------------- helpers ----------------
__device__ __forceinline__ ushort f2b(float f) {
    __hip_bfloat16 h = __float2bfloat16(f);
    return *reinterpret_cast<ushort*>(&h);
}
__device__ __forceinline__ float b2f(ushort u) {
    return __uint_as_float(((unsigned)u) << 16);
}
__device__ __forceinline__ void gload16(const ushort* g, ushort* l) {
    __builtin_amdgcn_global_load_lds(
        (const __attribute__((address_space(1))) void*)g,
        (__attribute__((address_space(3))) void*)l, 16, 0, 0);
}

// ============================================================================
// QKV: 256x128-tile NT GEMM, BK=32, 3-slot LDS ring (72 KB -> 2 blocks/CU),
// single barrier per K-tile, depth-2 prefetch, counted vmcnt.
// Best of 5 measured tile geometries (63.6 us / ~810 TF). Unchanged from r13.
// ============================================================================
__global__ __launch_bounds__(512, 4) void qkv_gemm256(
    const ushort* __restrict__ xb, const ushort* __restrict__ Wcat,
    const float* __restrict__ bk, const float* __restrict__ bq, const float* __restrict__ bv,
    ushort* __restrict__ Kb, ushort* __restrict__ Qb, ushort* __restrict__ Vt) {
    constexpr int T = 2048, C = 1024, K = 1024, NT = 32;
    __shared__ ushort smem[36864];  // 72 KB

    const int tid = threadIdx.x;
    const int l = tid & 63, w = tid >> 6;
    const int wm = (w >> 1) * 64, wn = (w & 1) * 64;   // 4M x 2N, 64x64/wave
    const int lr = l & 15, lk = l >> 4;

    const int b = blockIdx.x;                  // 768 = 8*96
    const int wg = (b & 7) * 96 + (b >> 3);    // XCD-bijective
    const int m0 = (wg / 24) * 256, n0 = (wg % 24) * 128;

    const int srow = w * 16 + (l >> 2);                      // 0..127
    const int scb = ((l & 3) << 4) ^ ((l & 32) ? 32 : 0);    // swizzled byte col
    const ushort* gA = xb + (size_t)(m0 + srow) * K + (scb >> 1);
    const ushort* gB = Wcat + (size_t)(n0 + srow) * K + (scb >> 1);

    const int LB = lr * 32 + ((lk << 3) ^ ((lr >= 8) ? 16 : 0));

    f32x4 acc[4][4] = {};

#define STAGEQ(tt, sl)                                                    \
    {                                                                     \
        const int _ko = (tt) * 32;                                        \
        ushort* _s = smem + (sl) * 12288 + w * 512;                       \
        gload16(gA + _ko,                   _s);                          \
        gload16(gA + (size_t)128 * K + _ko, _s + 4096);                   \
        gload16(gB + _ko,                   _s + 8192);                   \
    }

    STAGEQ(0, 0);
    STAGEQ(1, 1);
    asm volatile("s_waitcnt vmcnt(3)" ::: "memory");
    __builtin_amdgcn_s_barrier();
    asm volatile("" ::: "memory");

    int sc = 0, ss = 2;
    for (int t = 0; t < NT; ++t) {
        const ushort* slot = smem + sc * 12288;
        const ushort* Ab = slot + (wm >> 4) * 512 + LB;
        const ushort* Bb = slot + 8192 + (wn >> 4) * 512 + LB;
        short8 af[4], bf4[4];
#pragma unroll
        for (int f = 0; f < 4; ++f) af[f] = *reinterpret_cast<const short8*>(Ab + f * 512);
#pragma unroll
        for (int g = 0; g < 4; ++g) bf4[g] = *reinterpret_cast<const short8*>(Bb + g * 512);
        if (t + 2 < NT) STAGEQ(t + 2, ss);
        __builtin_amdgcn_s_setprio(1);
#pragma unroll
        for (int f = 0; f < 4; ++f)
#pragma unroll
            for (int g = 0; g < 4; ++g)
                acc[f][g] = __builtin_amdgcn_mfma_f32_16x16x32_bf16(af[f], bf4[g], acc[f][g], 0, 0, 0);
        __builtin_amdgcn_s_setprio(0);
        if (t + 1 < NT) {
            if (t + 2 < NT) asm volatile("s_waitcnt vmcnt(3)" ::: "memory");
            else            asm volatile("s_waitcnt vmcnt(0)" ::: "memory");
            __builtin_amdgcn_s_barrier();
            asm volatile("" ::: "memory");
        }
        sc = (sc == 2) ? 0 : sc + 1;
        ss = (ss == 2) ? 0 : ss + 1;
    }
#undef STAGEQ

    const int zsel = n0 >> 10;
    const int c0 = (n0 & 1023) + wn;
    if (zsel < 2) {
        ushort* O = (zsel == 0) ? Kb : Qb;
        const float* bias = (zsel == 0) ? bk : bq;
#pragma unroll
        for (int f = 0; f < 4; ++f)
#pragma unroll
            for (int g = 0; g < 4; ++g) {
                const int gc = c0 + g * 16 + lr;
                const float badd = bias[gc];
#pragma unroll
                for (int rr = 0; rr < 4; ++rr) {
                    const int gr = m0 + wm + f * 16 + lk * 4 + rr;
                    O[(size_t)gr * C + gc] = f2b(acc[f][g][rr] + badd);
                }
            }
    } else {
        const int zb = (m0 + wm) >> 11;
        const int s0 = (m0 + wm) & 2047;
        ushort* Vz = Vt + (size_t)zb * C * T;
#pragma unroll
        for (int f = 0; f < 4; ++f)
#pragma unroll
            for (int g = 0; g < 4; ++g) {
                const int gc = c0 + g * 16 + lr;
                const float badd = bv[gc];
                const int s = s0 + f * 16 + lk * 4;
                ushort tmp[4];
#pragma unroll
                for (int rr = 0; rr < 4; ++rr) tmp[rr] = f2b(acc[f][g][rr] + badd);
                *reinterpret_cast<uint2*>(Vz + (size_t)gc * T + s) =
                    *reinterpret_cast<uint2*>(tmp);
            }
    }
}

// ============================================================================
// 3-slot ring 128x128 NT GEMM for scores / PV.
// MODE 1 = scores: writes p' = exp(s/32) (0 above diag in diag blocks).
// MODE 2 = PV: ones-column MFMA row-sums; epilogue y = acc / rowsum.
//   PV pairing fix (r14): swizzle within each 256-half independently so
//   blockIdx pairs (b, b+256) — co-resident on one CU under round-robin
//   dispatch — carry complementary panels (i, 15-i): per-CU work uniform
//   at 68 K-tiles (was up to ~124 when the full-range swizzle broke pairing).
// ============================================================================
template <int MODE>
__global__ __launch_bounds__(256, 3) void gemm_ring(
    const ushort* __restrict__ Kb, const ushort* __restrict__ Qb,
    const ushort* __restrict__ Vt, ushort* __restrict__ Sb, float* __restrict__ out) {
    constexpr int T = 2048, C = 1024;
    __shared__ ushort smem[24576];  // 48 KB

    const int tid = threadIdx.x;
    const int l = tid & 63, w = tid >> 6;
    const int wm = (w >> 1) * 64, wn = (w & 1) * 64;
    const int lr = l & 15, lk = l >> 4;

    int m0, n0, nt, iblk = 0, jblk = 0, z = 0;
    const ushort *Au, *Bu;
    int ldA, ldB;
    if constexpr (MODE == 1) {
        const int wg0 = blockIdx.x;                  // 544 = 8*68
        const int wg = (wg0 & 7) * 68 + (wg0 >> 3);
        z = wg / 136; const int t136 = wg % 136;
        int i = (int)((sqrtf(8.f * t136 + 1.f) - 1.f) * 0.5f);
        while ((i + 1) * (i + 2) / 2 <= t136) ++i;
        while (i * (i + 1) / 2 > t136) --i;
        const int j = t136 - i * (i + 1) / 2;
        iblk = i; jblk = j;
        m0 = i * 128; n0 = j * 128;
        Au = Qb + (size_t)z * T * C + (size_t)m0 * C; ldA = C;
        Bu = Kb + (size_t)z * T * C + (size_t)n0 * C; ldB = C;
        nt = 32;
    } else {
        const int b0 = blockIdx.x;                   // 512
        const int h = b0 >> 8, s2 = b0 & 255;
        const int wg = (s2 & 7) * 32 + (s2 >> 3);    // XCD swizzle within half
        z = wg >> 6; const int r6 = wg & 63;
        const int nb = r6 & 7, ii = r6 >> 3;         // ii in 0..7
        const int i = h ? (15 - ii) : ii;            // pairs (b, b+256): i, 15-i
        iblk = i;
        m0 = i * 128; n0 = nb * 128;
        Au = Sb + (size_t)z * T * T + (size_t)m0 * T; ldA = T;
        Bu = Vt + (size_t)z * C * T + (size_t)n0 * T; ldB = T;
        nt = 4 * (i + 1);
    }

    const int srow = w * 16 + (l >> 2);
    const int scb = ((l & 3) << 4) ^ ((l >= 32) ? 32 : 0);
    const ushort* gA = Au + (size_t)srow * ldA + (scb >> 1);
    const ushort* gB = Bu + (size_t)srow * ldB + (scb >> 1);
    const size_t a64 = (size_t)64 * ldA, b64 = (size_t)64 * ldB;
    const int LBu = lr * 32 + ((lk << 3) ^ ((lr >= 8) ? 16 : 0));

    f32x4 acc[4][4] = {};
    f32x4 acc1[4] = {};
    short8 ones;
#pragma unroll
    for (int q = 0; q < 8; ++q) ones[q] = (short)0x3F80;  // bf16 1.0

#define STAGE(tt, sl)                                                    \
    {                                                                    \
        const int _ko = (tt) * 32;                                       \
        ushort* _d = smem + (sl) * 8192 + w * 512;                       \
        gload16(gA + _ko,        _d);                                    \
        gload16(gA + a64 + _ko,  _d + 2048);                             \
        gload16(gB + _ko,        _d + 4096);                             \
        gload16(gB + b64 + _ko,  _d + 6144);                             \
    }

    STAGE(0, 0);
    STAGE(1, 1);
    asm volatile("s_waitcnt vmcnt(4)" ::: "memory");
    __builtin_amdgcn_s_barrier();
    asm volatile("" ::: "memory");

    int sc = 0, ss = 2;
    for (int t = 0; t < nt; ++t) {
        const ushort* As = smem + sc * 8192 + (wm >> 4) * 512 + LBu;
        const ushort* Bs = smem + sc * 8192 + 4096 + (wn >> 4) * 512 + LBu;
        short8 af[4], bf[4];
#pragma unroll
        for (int q = 0; q < 4; ++q) {
            af[q] = *reinterpret_cast<const short8*>(As + q * 512);
            bf[q] = *reinterpret_cast<const short8*>(Bs + q * 512);
        }
        if (t + 2 < nt) STAGE(t + 2, ss);
        __builtin_amdgcn_s_setprio(1);
#pragma unroll
        for (int mf = 0; mf < 4; ++mf)
#pragma unroll
            for (int nf = 0; nf < 4; ++nf)
                acc[mf][nf] = __builtin_amdgcn_mfma_f32_16x16x32_bf16(af[mf], bf[nf], acc[mf][nf], 0, 0, 0);
        if constexpr (MODE == 2) {
#pragma unroll
            for (int mf = 0; mf < 4; ++mf)
                acc1[mf] = __builtin_amdgcn_mfma_f32_16x16x32_bf16(af[mf], ones, acc1[mf], 0, 0, 0);
        }
        __builtin_amdgcn_s_setprio(0);
        if (t + 1 < nt) {
            if (t + 2 < nt) asm volatile("s_waitcnt vmcnt(4)" ::: "memory");
            else            asm volatile("s_waitcnt vmcnt(0)" ::: "memory");
            __builtin_amdgcn_s_barrier();
            asm volatile("" ::: "memory");
        }
        sc = (sc == 2) ? 0 : sc + 1;
        ss = (ss == 2) ? 0 : ss + 1;
    }
#undef STAGE

    if constexpr (MODE == 1) {
        ushort* Sp = Sb + (size_t)z * T * T;
        const bool diag = (iblk == jblk);
#pragma unroll
        for (int mf = 0; mf < 4; ++mf)
#pragma unroll
            for (int nf = 0; nf < 4; ++nf) {
                const int gc = n0 + wn + nf * 16 + lr;
#pragma unroll
                for (int rr = 0; rr < 4; ++rr) {
                    const int gr = m0 + wm + mf * 16 + lk * 4 + rr;
                    float p = __expf(acc[mf][nf][rr] * 0.03125f);
                    if (diag && gc > gr) p = 0.f;
                    Sp[(size_t)gr * T + gc] = f2b(p);
                }
            }
    } else {
        float* Op = out + (size_t)z * T * C;
#pragma unroll
        for (int mf = 0; mf < 4; ++mf)
#pragma unroll
            for (int rr = 0; rr < 4; ++rr) {
                const int gr = m0 + wm + mf * 16 + lk * 4 + rr;
                const float inv = 1.0f / acc1[mf][rr];
#pragma unroll
                for (int nf = 0; nf < 4; ++nf) {
                    const int gc = n0 + wn + nf * 16 + lr;
                    Op[(size_t)gr * C + gc] = acc[mf][nf][rr] * inv;
                }
            }
    }
}

// ---- fused fp32 -> bf16 convert for x, Wk, Wq, Wv ----
__global__ __launch_bounds__(256) void cvt_all(
    const float* __restrict__ x, const float* __restrict__ Wk,
    const float* __restrict__ Wq, const float* __restrict__ Wv,
    ushort* __restrict__ xb, ushort* __restrict__ Wcat) {
    constexpr int C = 1024;
    constexpr int NX = 8388608 / 8, NW = C * C / 8;
    int i = blockIdx.x * 256 + threadIdx.x;
    const float* src; ushort* dst;
    if (i < NX)               { src = x;  dst = xb; }
    else if (i < NX + NW)     { src = Wk; dst = Wcat;                 i -= NX; }
    else if (i < NX + 2 * NW) { src = Wq; dst = Wcat + (size_t)C * C; i -= NX + NW; }
    else                      { src = Wv; dst = Wcat + 2 * (size_t)C * C; i -= NX + 2 * NW; }
    const float4* p = reinterpret_cast<const float4*>(src) + (size_t)i * 2;
    float4 a = p[0], b = p[1];
    ushort o[8] = {f2b(a.x), f2b(a.y), f2b(a.z), f2b(a.w),
                   f2b(b.x), f2b(b.y), f2b(b.z), f2b(b.w)};
    reinterpret_cast<uint4*>(dst)[i] = *reinterpret_cast<uint4*>(o);
}

extern "C" void kernel_launch(void* const* d_in, const int* in_sizes, int n_in,
                              void* d_out, int out_size, void* d_ws, size_t ws_size,
                              hipStream_t stream) {
    const float* x  = (const float*)d_in[0];
    const float* Wk = (const float*)d_in[1];
    const float* bk = (const float*)d_in[2];
    const float* Wq = (const float*)d_in[3];
    const float* bq = (const float*)d_in[4];
    const float* Wv = (const float*)d_in[5];
    const float* bv = (const float*)d_in[6];
    float* out = (float*)d_out;

    constexpr int B = 4, T = 2048, C = 1024;
    constexpr size_t BTC = (size_t)B * T * C;  // 8388608

    ushort* Kb = (ushort*)d_ws;
    ushort* Qb = Kb + BTC;
    ushort* Vt = Qb + BTC;                      // V stored transposed [B][C][T]
    ushort* Sb = Vt + BTC;                      // B*T*T ushorts (holds P' = exp)
    ushort* xb   = Sb;                          // aliased (dead before scores)
    ushort* Wcat = Sb + BTC;

    dim3 blk(256);

    // 0) fp32 -> bf16 (single fused launch)
    cvt_all<<<dim3(5632), blk, 0, stream>>>(x, Wk, Wq, Wv, xb, Wcat);

    // 1) fused QKV projection (256x128, BK=32 ring-3, 2 blocks/CU)
    qkv_gemm256<<<dim3(768), dim3(512), 0, stream>>>(xb, Wcat, bk, bq, bv, Kb, Qb, Vt);

    // 2) scores -> P' = exp(s/32), causal (lower-triangle blocks; full diag tiles)
    gemm_ring<1><<<dim3(544), blk, 0, stream>>>(Kb, Qb, Vt, Sb, out);

    // 3) y = (P' @ V) / rowsum(P')  -- softmax normalization fused via ones-MFMA
    gemm_ring<2><<<dim3(512), blk, 0, stream>>>(Kb, Qb, Vt, Sb, out);
}